// Round 4
// baseline (369.448 us; speedup 1.0000x reference)
//
#include <hip/hip_runtime.h>
#include <hip/hip_bf16.h>

// Autoregressive LSTM: B=16384, T=60, D=34, E=128, H=64, n_seeds=10
// Persistent block = 32 batch rows x 60 steps, 4 waves, 512 blocks (2/CU).
// R4: swapped-operand MFMA (A=weights, B=activations) -> D has batch in lanes,
// features in acc regs: all LDS/global epilogue writes contiguous (b64/dwordx2),
// packed bf16 converts. Weight reg layouts & LDS read patterns unchanged.

typedef float f32x4 __attribute__((ext_vector_type(4)));
typedef float f32x2 __attribute__((ext_vector_type(2)));
typedef __bf16 bf16x8 __attribute__((ext_vector_type(8)));
typedef unsigned short u16x8 __attribute__((ext_vector_type(8)));
typedef unsigned short u16x4 __attribute__((ext_vector_type(4)));

#define MFMA_BF16(A, B, C) \
    __builtin_amdgcn_mfma_f32_16x16x32_bf16(__builtin_bit_cast(bf16x8, (A)), \
                                            __builtin_bit_cast(bf16x8, (B)), (C), 0, 0, 0)

__device__ __forceinline__ unsigned short f2b(float f) {
    return __builtin_bit_cast(unsigned short, (__bf16)f);
}
__device__ __forceinline__ float exp2_(float x) {
#if __has_builtin(__builtin_amdgcn_exp2f)
    return __builtin_amdgcn_exp2f(x);
#else
    return __exp2f(x);
#endif
}
__device__ __forceinline__ float rcp_(float x) {
    return __builtin_amdgcn_rcpf(x);
}
__device__ __forceinline__ float sig_(float x) {
    return rcp_(1.0f + exp2_(-1.44269504f * x));
}
__device__ __forceinline__ float tanh_(float x) {
    return __builtin_fmaf(2.0f, rcp_(1.0f + exp2_(-2.88539008f * x)), -1.0f);
}

__global__ __launch_bounds__(256, 2) void ar_lstm_kernel(
    const float* __restrict__ x,      // (16384,60,34)
    const float* __restrict__ W_enc,  // (128,34)
    const float* __restrict__ b_enc,  // (128)
    const float* __restrict__ W_ih,   // (256,128)
    const float* __restrict__ W_hh,   // (256,64)
    const float* __restrict__ b_ih,   // (256)
    const float* __restrict__ b_hh,   // (256)
    const float* __restrict__ W_dec,  // (34,64)
    const float* __restrict__ b_dec,  // (34)
    float* __restrict__ out)          // (16384,50,34)
{
    __shared__ __attribute__((aligned(16))) unsigned short x_s[32][136];    // rnn_in (M x 128)
    __shared__ __attribute__((aligned(16))) unsigned short h_s[2][32][72];  // h double-buffered
    __shared__ __attribute__((aligned(16))) unsigned short d_s[2][32][72];  // seed input staging
    __shared__ __attribute__((aligned(16))) float wdec_f[34][64];           // W_dec fp32 (init only)
    __shared__ float bdec_f[34];

    const int tid = threadIdx.x;
    const int w  = tid >> 6;   // wave 0..3
    const int l  = tid & 63;
    const int lr = l & 15;     // lane row: batch index within m-tile (D cols)
    const int lg = l >> 4;     // lane group: feature quartet selector (D rows)
    const int b0 = blockIdx.x * 32;

    for (int i = tid; i < 32 * 136;    i += 256) (&x_s[0][0])[i] = 0;
    for (int i = tid; i < 2 * 32 * 72; i += 256) (&h_s[0][0][0])[i] = 0;
    for (int i = tid; i < 2 * 32 * 72; i += 256) (&d_s[0][0][0])[i] = 0;
    for (int i = tid; i < 34 * 64;     i += 256) (&wdec_f[0][0])[i] = W_dec[i];
    if (tid < 34) bdec_f[tid] = b_dec[tid];
    for (int e = tid; e < 32 * 34; e += 256) {
        int r = e / 34, d = e - r * 34;
        d_s[0][r][d] = f2b(x[((b0 + r) * 60 + 0) * 34 + d]);
    }

    // ---- weight A-fragments in registers (layouts unchanged from B-frag form) ----
    u16x8 wg[4][6];
    for (int g = 0; g < 4; ++g) {
        int n = (w + 4 * g) * 16 + lr;
        for (int kt = 0; kt < 4; ++kt)
            for (int i = 0; i < 8; ++i)
                wg[g][kt][i] = f2b(W_ih[n * 128 + kt * 32 + lg * 8 + i]);
        for (int kt = 0; kt < 2; ++kt)
            for (int i = 0; i < 8; ++i)
                wg[g][4 + kt][i] = f2b(W_hh[n * 64 + kt * 32 + lg * 8 + i]);
    }
    u16x8 we[2][2];
    for (int ntl = 0; ntl < 2; ++ntl) {
        int n = (w * 2 + ntl) * 16 + lr;
        for (int kt = 0; kt < 2; ++kt)
            for (int i = 0; i < 8; ++i) {
                int k = kt * 32 + lg * 8 + i;
                we[ntl][kt][i] = (k < 34) ? f2b(W_enc[n * 34 + k]) : (unsigned short)0;
            }
    }
    u16x8 wd[2];
    {
        int n = w * 16 + lr;
        bool v = (w < 3) && (n < 34);
        for (int kt = 0; kt < 2; ++kt)
            for (int i = 0; i < 8; ++i)
                wd[kt][i] = v ? f2b(W_dec[n * 64 + kt * 32 + lg * 8 + i]) : (unsigned short)0;
    }

    // ---- bias vectors: D layout => bias varies across acc regs (lg*4+r) ----
    f32x4 bias_gv[4];
    for (int g = 0; g < 4; ++g) {
        int nb = (w + 4 * g) * 16 + lg * 4;
        for (int r = 0; r < 4; ++r) bias_gv[g][r] = b_ih[nb + r] + b_hh[nb + r];
    }
    f32x4 bias_ev[2];
    for (int ntl = 0; ntl < 2; ++ntl) {
        int nb = (w * 2 + ntl) * 16 + lg * 4;
        for (int r = 0; r < 4; ++r) bias_ev[ntl][r] = b_enc[nb + r];
    }
    f32x4 bias_dv;
    for (int r = 0; r < 4; ++r) {
        int nd = w * 16 + lg * 4 + r;
        bias_dv[r] = (w < 3 && nd < 34) ? b_dec[nd] : 0.0f;
    }

    __syncthreads();

    // ---- fused W' = W_enc @ W_dec (A-frag layout, rows n = tile*16+lr) ----
    u16x8 wf[2][2];
    for (int ntl = 0; ntl < 2; ++ntl) {
        int n = (w * 2 + ntl) * 16 + lr;
        f32x4 av0 = {0,0,0,0}, av1 = {0,0,0,0}, av2 = {0,0,0,0}, av3 = {0,0,0,0};
        for (int j = 0; j < 34; ++j) {
            float wej = W_enc[n * 34 + j];
            av0 += wej * *(const f32x4*)&wdec_f[j][lg * 8];
            av1 += wej * *(const f32x4*)&wdec_f[j][lg * 8 + 4];
            av2 += wej * *(const f32x4*)&wdec_f[j][32 + lg * 8];
            av3 += wej * *(const f32x4*)&wdec_f[j][32 + lg * 8 + 4];
        }
        for (int i = 0; i < 4; ++i) {
            wf[ntl][0][i]     = f2b(av0[i]);
            wf[ntl][0][4 + i] = f2b(av1[i]);
            wf[ntl][1][i]     = f2b(av2[i]);
            wf[ntl][1][4 + i] = f2b(av3[i]);
        }
    }
    // bias' = b_enc + W_enc @ b_dec, rows nb+r (bias layout, not frag layout)
    f32x4 bias_fv[2];
    for (int ntl = 0; ntl < 2; ++ntl) {
        int nb = (w * 2 + ntl) * 16 + lg * 4;
        for (int r = 0; r < 4; ++r) {
            float s = b_enc[nb + r];
            for (int j = 0; j < 34; ++j) s += W_enc[(nb + r) * 34 + j] * bdec_f[j];
            bias_fv[ntl][r] = s;
        }
    }

    float c_st[2][4], prev[2][4];
    for (int mt = 0; mt < 2; ++mt)
        for (int r = 0; r < 4; ++r) { c_st[mt][r] = 0.0f; prev[mt][r] = 0.0f; }

    const int nd0 = w * 16 + lg * 4;  // dec/out column base for this lane
    float* outp[2];
    outp[0] = out; outp[1] = out;     // set properly at t==9

    for (int t = 0; t < 60; ++t) {
        const int hw = t & 1;
        const int hr = hw ^ 1;

        if (t < 10) {
            // seed encode: emb^T = W_enc @ x^T
            u16x8 bd[2][2];
            for (int mt = 0; mt < 2; ++mt)
                for (int kt = 0; kt < 2; ++kt)
                    bd[mt][kt] = *(const u16x8*)&d_s[hw][mt * 16 + lr][kt * 32 + lg * 8];
            for (int mt = 0; mt < 2; ++mt)
                for (int ntl = 0; ntl < 2; ++ntl) {
                    f32x4 a = bias_ev[ntl];
                    a = MFMA_BF16(we[ntl][0], bd[mt][0], a);
                    a = MFMA_BF16(we[ntl][1], bd[mt][1], a);
                    u16x4 pv;
                    for (int r = 0; r < 4; ++r) pv[r] = f2b(fmaxf(a[r], 0.0f));
                    *(u16x4*)&x_s[mt * 16 + lr][(w * 2 + ntl) * 16 + lg * 4] = pv;
                }
            if (t + 1 < 10)
                for (int e = tid; e < 32 * 34; e += 256) {
                    int r = e / 34, d = e - r * 34;
                    d_s[hr][r][d] = f2b(x[((b0 + r) * 60 + (t + 1)) * 34 + d]);
                }
            __syncthreads();
        }

        // ---- gates: G^T = [W_ih|W_hh] @ [x|h]^T, then cell ----
        for (int mt = 0; mt < 2; ++mt) {
            u16x8 bx[4], bh[2];
            for (int kt = 0; kt < 4; ++kt)
                bx[kt] = *(const u16x8*)&x_s[mt * 16 + lr][kt * 32 + lg * 8];
            for (int kt = 0; kt < 2; ++kt)
                bh[kt] = *(const u16x8*)&h_s[hr][mt * 16 + lr][kt * 32 + lg * 8];
            f32x4 acc[4];
            for (int g = 0; g < 4; ++g) {
                f32x4 a = bias_gv[g];
                a = MFMA_BF16(wg[g][0], bx[0], a);
                a = MFMA_BF16(wg[g][1], bx[1], a);
                a = MFMA_BF16(wg[g][2], bx[2], a);
                a = MFMA_BF16(wg[g][3], bx[3], a);
                a = MFMA_BF16(wg[g][4], bh[0], a);
                a = MFMA_BF16(wg[g][5], bh[1], a);
                acc[g] = a;
            }
            // cell: this lane owns batch (mt*16+lr), h-cols w*16+lg*4..+3
            u16x4 hv;
            for (int r = 0; r < 4; ++r) {
                float cn = sig_(acc[1][r]) * c_st[mt][r] + sig_(acc[0][r]) * tanh_(acc[2][r]);
                float hn = sig_(acc[3][r]) * tanh_(cn);
                c_st[mt][r] = cn;
                hv[r] = f2b(hn);
            }
            *(u16x4*)&h_s[hw][mt * 16 + lr][w * 16 + lg * 4] = hv;
        }
        __syncthreads();

        if (t >= 9) {
            u16x8 bh2[2][2];
            for (int mt = 0; mt < 2; ++mt)
                for (int kt = 0; kt < 2; ++kt)
                    bh2[mt][kt] = *(const u16x8*)&h_s[hw][mt * 16 + lr][kt * 32 + lg * 8];

            if (t == 9) {
                for (int mt = 0; mt < 2; ++mt) {
                    int row = b0 + mt * 16 + lr;
                    outp[mt] = out + (size_t)row * 50 * 34 + nd0;
                    const float* px = &x[((size_t)row * 60 + 9) * 34 + nd0];
                    if (w < 2) {
                        f32x2 p01 = *(const f32x2*)px;
                        f32x2 p23 = *(const f32x2*)(px + 2);
                        prev[mt][0] = p01[0]; prev[mt][1] = p01[1];
                        prev[mt][2] = p23[0]; prev[mt][3] = p23[1];
                    } else if (w == 2 && lg == 0) {
                        f32x2 p01 = *(const f32x2*)px;   // cols 32,33
                        prev[mt][0] = p01[0]; prev[mt][1] = p01[1];
                    }
                }
            } else if (w < 3) {
                // dec^T = W_dec @ h^T; out = dec + prev (fp32 carry)
                for (int mt = 0; mt < 2; ++mt) {
                    f32x4 a = bias_dv;
                    a = MFMA_BF16(wd[0], bh2[mt][0], a);
                    a = MFMA_BF16(wd[1], bh2[mt][1], a);
                    if (w < 2) {
                        float o0 = a[0] + prev[mt][0], o1 = a[1] + prev[mt][1];
                        float o2 = a[2] + prev[mt][2], o3 = a[3] + prev[mt][3];
                        prev[mt][0] = o0; prev[mt][1] = o1;
                        prev[mt][2] = o2; prev[mt][3] = o3;
                        f32x2 s01 = {o0, o1}, s23 = {o2, o3};
                        *(f32x2*)(outp[mt])     = s01;
                        *(f32x2*)(outp[mt] + 2) = s23;
                    } else if (lg == 0) {               // cols 32,33
                        float o0 = a[0] + prev[mt][0], o1 = a[1] + prev[mt][1];
                        prev[mt][0] = o0; prev[mt][1] = o1;
                        f32x2 s01 = {o0, o1};
                        *(f32x2*)(outp[mt]) = s01;
                    }
                }
            }
            if (t > 9) { outp[0] += 34; outp[1] += 34; }

            if (t < 59) {
                // rnn_in^T = relu(W' @ h^T + b')
                for (int mt = 0; mt < 2; ++mt)
                    for (int ntl = 0; ntl < 2; ++ntl) {
                        f32x4 a = bias_fv[ntl];
                        a = MFMA_BF16(wf[ntl][0], bh2[mt][0], a);
                        a = MFMA_BF16(wf[ntl][1], bh2[mt][1], a);
                        u16x4 pv;
                        for (int r = 0; r < 4; ++r) pv[r] = f2b(fmaxf(a[r], 0.0f));
                        *(u16x4*)&x_s[mt * 16 + lr][(w * 2 + ntl) * 16 + lg * 4] = pv;
                    }
            }
            __syncthreads();
        }
    }
}

extern "C" void kernel_launch(void* const* d_in, const int* in_sizes, int n_in,
                              void* d_out, int out_size, void* d_ws, size_t ws_size,
                              hipStream_t stream) {
    const float* x     = (const float*)d_in[0];
    const float* W_enc = (const float*)d_in[1];
    const float* b_enc = (const float*)d_in[2];
    const float* W_ih  = (const float*)d_in[3];
    const float* W_hh  = (const float*)d_in[4];
    const float* b_ih  = (const float*)d_in[5];
    const float* b_hh  = (const float*)d_in[6];
    const float* W_dec = (const float*)d_in[7];
    const float* b_dec = (const float*)d_in[8];
    float* out = (float*)d_out;
    // n_seeds (d_in[9]) is compile-time 10 for this problem shape.
    ar_lstm_kernel<<<512, 256, 0, stream>>>(x, W_enc, b_enc, W_ih, W_hh,
                                            b_ih, b_hh, W_dec, b_dec, out);
}